// Round 5
// baseline (3041.187 us; speedup 1.0000x reference)
//
#include <hip/hip_runtime.h>
#include <math.h>

#define NB 8
#define NP 4096
#define FEAT_SZ (NB * NP * 128)
#define INVBN 0.9999950000374999f  // 1/sqrt(1+1e-5), f32-rounded
#define SPLIT 2
#define CHUNKS (64 / SPLIT)

typedef unsigned long long u64;
typedef unsigned int u32;

// monotone map: float -> u32 preserving order (larger float -> larger u32)
__device__ __forceinline__ u32 fmap(float f) {
    u32 b = __float_as_uint(f);
    return b ^ ((u32)((int)b >> 31) | 0x80000000u);
}

__device__ __forceinline__ u64 umax64(u64 a, u64 b) { return a > b ? a : b; }

// insert key into descending-sorted v[16] if it beats the current 16th.
// key = (mapped_dist << 32) | ~m  -> tie-break: equal dist => smaller m wins.
__device__ __forceinline__ void kins(u64 (&v)[16], u64 key) {
    if (key <= v[15]) return;
    bool bb[16];
#pragma unroll
    for (int j = 0; j < 16; ++j) bb[j] = key > v[j];
#pragma unroll
    for (int j = 15; j >= 1; --j) v[j] = bb[j] ? (bb[j - 1] ? v[j - 1] : key) : v[j];
    if (bb[0]) v[0] = key;
}

// 4-deep register buffer append (static cndmask chain); overflow -> direct kins
__device__ __forceinline__ void bufpush(u64 (&v)[16], u64 &q0, u64 &q1, u64 &q2, u64 &q3,
                                        int &cnt, u64 key) {
    if (cnt < 4) {
        q0 = cnt == 0 ? key : q0;
        q1 = cnt == 1 ? key : q1;
        q2 = cnt == 2 ? key : q2;
        q3 = cnt == 3 ? key : q3;
        ++cnt;
    } else {
        kins(v, key);   // rare overflow fallback (exactness guarantee)
    }
}

__device__ __forceinline__ void bufflush(u64 (&v)[16], u64 &q0, u64 &q1, u64 &q2, u64 &q3,
                                         int &cnt) {
    kins(v, q0); kins(v, q1); kins(v, q2); kins(v, q3);
    q0 = 0; q1 = 0; q2 = 0; q3 = 0; cnt = 0;
}

// bitonic clean (desc) of a bitonic 16-sequence -> fully sorted desc
__device__ __forceinline__ void bclean(u64 (&v)[16]) {
#pragma unroll
    for (int d = 8; d; d >>= 1) {
#pragma unroll
        for (int i = 0; i < 16; ++i) {
            if ((i & d) == 0) {
                u64 a = v[i], b = v[i | d];
                bool s = a < b;
                v[i] = s ? b : a;
                v[i | d] = s ? a : b;
            }
        }
    }
}

// merge partner lane's sorted-16 (lane+off) into mine: pairwise-max + clean
__device__ __forceinline__ void merge_shfl(u64 (&v)[16], int off) {
    u64 o[16];
#pragma unroll
    for (int j = 0; j < 16; ++j) o[j] = __shfl_down(v[j], off);
#pragma unroll
    for (int j = 0; j < 16; ++j) {
        u64 b = o[15 - j];
        v[j] = v[j] > b ? v[j] : b;
    }
    bclean(v);
}

// max over the 8 consecutive lanes of a row
__device__ __forceinline__ u64 rowmax8(u64 x) {
    x = umax64(x, __shfl_xor(x, 1));
    x = umax64(x, __shfl_xor(x, 2));
    x = umax64(x, __shfl_xor(x, 4));
    return x;
}

// ---------------- kernel A: point-space kNN (k=16) ----------------
// grid 8*128, block 256. 32 rows/block, 8 threads/row (interleaved m-partition).
// Buffered selection: gate vs row-t-hat, 4-deep buffer, amortized flush.
__global__ __launch_bounds__(256) void knn_point_kernel(const float* __restrict__ point,
                                                        int* __restrict__ idxP) {
    __shared__ float4 pts[NP];  // (x,y,z,xx)  64 KiB
    int bt = blockIdx.x >> 7;
    int n0 = (blockIdx.x & 127) << 5;
    const float* pb = point + (size_t)bt * 3 * NP;
    for (int m = threadIdx.x; m < NP; m += 256) {
        float x = pb[m], y = pb[NP + m], z = pb[2 * NP + m];
        pts[m] = make_float4(x, y, z, fmaf(z, z, fmaf(y, y, x * x)));
    }
    __syncthreads();
    int t = threadIdx.x;
    int q = t & 7;
    float4 c = pts[n0 + (t >> 3)];
    u64 v[16];
#pragma unroll
    for (int j = 0; j < 16; ++j) v[j] = 0;
    u64 b0 = 0, b1 = 0, b2 = 0, b3 = 0;
    int cnt = 0;
    u64 th = 0;
#pragma unroll 1
    for (int o = 0; o < 8; ++o) {
#pragma unroll 4
        for (int ii = 0; ii < 64; ++ii) {
            int m = (((o << 6) + ii) << 3) + q;
            float4 p = pts[m];
            float inner = fmaf(c.z, p.z, fmaf(c.y, p.y, c.x * p.x));
            float pd = fmaf(2.0f, inner, -c.w) - p.w;  // 2*inner - xx_n - xx_m
            u64 key = ((u64)fmap(pd) << 32) | (u64)(u32)~m;
            if (key > th) bufpush(v, b0, b1, b2, b3, cnt, key);
        }
        if (__any(cnt >= 3)) {
            bufflush(v, b0, b1, b2, b3, cnt);
            th = rowmax8(v[15]);
        }
    }
    bufflush(v, b0, b1, b2, b3, cnt);
    merge_shfl(v, 4);
    merge_shfl(v, 2);
    merge_shfl(v, 1);
    if (q == 0) {
        int* op = idxP + ((size_t)bt * NP + n0 + (t >> 3)) * 16;
#pragma unroll
        for (int j = 0; j < 16; ++j) op[j] = (int)~(u32)v[j];
    }
}

// ---------- kernel B: edge-conv1_1(k=8) + 1_2(k=16) + conv1_3, fused ----------
__global__ __launch_bounds__(256) void edge12_conv13_kernel(
    const float* __restrict__ point, const int* __restrict__ idxP,
    const float* __restrict__ w11, const float* __restrict__ b11,
    const float* __restrict__ g11, const float* __restrict__ bb11,
    const float* __restrict__ w12, const float* __restrict__ b12,
    const float* __restrict__ g12, const float* __restrict__ bb12,
    const float* __restrict__ w13, const float* __restrict__ b13,
    const float* __restrict__ g13, const float* __restrict__ bb13,
    float* __restrict__ h1t, float* __restrict__ xxf) {
    __shared__ float wl[128 * 64];
    for (int i = threadIdx.x; i < 128 * 64; i += 256) wl[i] = w13[i];
    __syncthreads();
    int lane = threadIdx.x & 63;
    int pt = blockIdx.x * 4 + (threadIdx.x >> 6);
    int bt = pt >> 12, n = pt & (NP - 1);
    const float* pb = point + (size_t)bt * 3 * NP;
    float wd1[3], wc1[3], wd2[3], wc2[3];
#pragma unroll
    for (int c = 0; c < 3; ++c) {
        wd1[c] = w11[c * 64 + lane]; wc1[c] = w11[(3 + c) * 64 + lane];
        wd2[c] = w12[c * 64 + lane]; wc2[c] = w12[(3 + c) * 64 + lane];
    }
    float s1 = g11[lane] * INVBN, sh1 = bb11[lane];
    float s2 = g12[lane] * INVBN, sh2 = bb12[lane];
    float cx = pb[n], cy = pb[NP + n], cz = pb[2 * NP + n];
    float base1 = fmaf(wc1[2], cz, fmaf(wc1[1], cy, fmaf(wc1[0], cx, b11[lane])));
    float base2 = fmaf(wc2[2], cz, fmaf(wc2[1], cy, fmaf(wc2[0], cx, b12[lane])));
    float a1 = -INFINITY, a2 = -INFINITY;
    const int* nb = idxP + (size_t)pt * 16;
#pragma unroll
    for (int j = 0; j < 16; ++j) {
        int m = nb[j];
        float ex = pb[m] - cx, ey = pb[NP + m] - cy, ez = pb[2 * NP + m] - cz;
        float y2 = fmaf(wd2[2], ez, fmaf(wd2[1], ey, fmaf(wd2[0], ex, base2)));
        float z2 = fmaf(y2, s2, sh2);
        z2 = z2 >= 0.f ? z2 : 0.2f * z2;
        a2 = fmaxf(a2, z2);
        if (j < 8) {  // top-8 is prefix of sorted top-16
            float y1 = fmaf(wd1[2], ez, fmaf(wd1[1], ey, fmaf(wd1[0], ex, base1)));
            float z1 = fmaf(y1, s1, sh1);
            z1 = z1 >= 0.f ? z1 : 0.2f * z1;
            a1 = fmaxf(a1, z1);
        }
    }
    float acc = b13[lane];
#pragma unroll
    for (int c = 0; c < 64; ++c) acc = fmaf(wl[c * 64 + lane], __shfl(a1, c), acc);
#pragma unroll
    for (int c = 0; c < 64; ++c) acc = fmaf(wl[(64 + c) * 64 + lane], __shfl(a2, c), acc);
    float h = fmaf(acc, g13[lane] * INVBN, bb13[lane]);
    h = h >= 0.f ? h : 0.2f * h;
    h1t[((size_t)pt << 6) + lane] = h;
    // xxf: ascending-FMA chain, bitwise-identical to the GEMM diagonal chain
    float s = 0.f;
#pragma unroll
    for (int c = 0; c < 64; ++c) { float hc = __shfl(h, c); s = fmaf(hc, hc, s); }
    if (lane == 0) xxf[pt] = s;
}

// ---------------- kernel C: feature-space kNN (C=64, k=16) ----------------
// grid 8*64*SPLIT, block 256, NO LDS, no barriers. A and B fragments read
// directly from global (h1t is [row][K], read along K in float4; B-panel is
// L2-resident at 1 MB/batch). Thread = 2 rows x 8 cols; buffered selection.
__global__ __launch_bounds__(256, 3) void knn_feat_kernel(const float* __restrict__ h1t,
                                                          const float* __restrict__ xxf,
                                                          u64* __restrict__ partF) {
    int seg = blockIdx.x & (SPLIT - 1);
    int rg  = (blockIdx.x >> 1) & 63;
    int bt  = blockIdx.x >> 7;
    int n0 = rg << 6;
    int tid = threadIdx.x;
    int cg = tid & 7;
    int ar = (tid >> 3) << 1;               // my two rows (local 0..62)
    const float* hbase = h1t + ((size_t)bt * NP << 6);
    const float* Ar0 = hbase + ((size_t)(n0 + ar) << 6);
    const float* Ar1 = Ar0 + 64;
    float xa0 = xxf[bt * NP + n0 + ar];
    float xa1 = xxf[bt * NP + n0 + ar + 1];
    u64 v[2][16];
#pragma unroll
    for (int j = 0; j < 16; ++j) { v[0][j] = 0; v[1][j] = 0; }
    u64 a0 = 0, a1 = 0, a2 = 0, a3 = 0;   // row-0 buffer
    u64 c0 = 0, c1 = 0, c2 = 0, c3 = 0;   // row-1 buffer
    int cA = 0, cB = 0;
    u64 t0 = 0, t1 = 0;
#pragma unroll 1
    for (int mcl = 0; mcl < CHUNKS; ++mcl) {
        int m0 = ((seg * CHUNKS) + mcl) << 6;
        const float* Bc = hbase + ((size_t)(m0 + (cg << 3)) << 6);
        const float* xbp = xxf + bt * NP + m0 + (cg << 3);
        float4 x0 = *(const float4*)xbp;
        float4 x1 = *(const float4*)(xbp + 4);
        float acc[2][8];
#pragma unroll
        for (int j = 0; j < 8; ++j) { acc[0][j] = 0.f; acc[1][j] = 0.f; }
#pragma unroll 1
        for (int kb = 0; kb < 16; ++kb) {
            int kk = kb << 2;
            float4 fa0 = *(const float4*)(Ar0 + kk);
            float4 fa1 = *(const float4*)(Ar1 + kk);
            float4 fb[8];
#pragma unroll
            for (int c = 0; c < 8; ++c) fb[c] = *(const float4*)(Bc + (c << 6) + kk);
            // ascending-kk chains (x,y,z,w innermost-first) -> bitwise == xxf diag
#pragma unroll
            for (int c = 0; c < 8; ++c) {
                acc[0][c] = fmaf(fa0.w, fb[c].w, fmaf(fa0.z, fb[c].z,
                              fmaf(fa0.y, fb[c].y, fmaf(fa0.x, fb[c].x, acc[0][c]))));
                acc[1][c] = fmaf(fa1.w, fb[c].w, fmaf(fa1.z, fb[c].z,
                              fmaf(fa1.y, fb[c].y, fmaf(fa1.x, fb[c].x, acc[1][c]))));
            }
        }
        // buffered selection from registers, gated by shared row threshold
        u32 klo = ~(u32)(m0 + (cg << 3));
        float xb[8] = {x0.x, x0.y, x0.z, x0.w, x1.x, x1.y, x1.z, x1.w};
#pragma unroll
        for (int j = 0; j < 8; ++j) {
            float pd0 = fmaf(2.0f, acc[0][j], -xa0) - xb[j];
            u64 k0 = ((u64)fmap(pd0) << 32) | (u64)(klo - (u32)j);
            if (k0 > t0) bufpush(v[0], a0, a1, a2, a3, cA, k0);
            float pd1 = fmaf(2.0f, acc[1][j], -xa1) - xb[j];
            u64 k1 = ((u64)fmap(pd1) << 32) | (u64)(klo - (u32)j);
            if (k1 > t1) bufpush(v[1], c0, c1, c2, c3, cB, k1);
        }
        if (__any((cA >= 3) || (cB >= 3))) {
            bufflush(v[0], a0, a1, a2, a3, cA);
            bufflush(v[1], c0, c1, c2, c3, cB);
            t0 = rowmax8(v[0][15]);
            t1 = rowmax8(v[1][15]);
        }
    }
    bufflush(v[0], a0, a1, a2, a3, cA);
    bufflush(v[1], c0, c1, c2, c3, cB);
    // merge 8 partial lists per row (lanes rp*8+cg, cg=0..7) via shfl tree
#pragma unroll
    for (int i = 0; i < 2; ++i) {
        merge_shfl(v[i], 4);
        merge_shfl(v[i], 2);
        merge_shfl(v[i], 1);
    }
    if (cg == 0) {
#pragma unroll
        for (int i = 0; i < 2; ++i) {
            u64* op = partF + (((size_t)bt * NP + n0 + ar + i) * SPLIT + seg) * 16;
#pragma unroll
            for (int j = 0; j < 16; ++j) op[j] = v[i][j];
        }
    }
}

// ---------------- kernel C2: merge the SPLIT partial lists per row ----------------
__global__ __launch_bounds__(256) void mergeF_kernel(const u64* __restrict__ partF,
                                                     int* __restrict__ idxF) {
    int r = blockIdx.x * 256 + threadIdx.x;   // 0..NB*NP-1
    const u64* base = partF + (size_t)r * (SPLIT * 16);
    u64 a[16];
#pragma unroll
    for (int j = 0; j < 16; ++j) a[j] = base[j];
    u64 b[16];
#pragma unroll
    for (int j = 0; j < 16; ++j) b[j] = base[16 + j];
#pragma unroll
    for (int j = 0; j < 16; ++j) {
        u64 x = b[15 - j];
        a[j] = a[j] > x ? a[j] : x;
    }
    bclean(a);
    int* op = idxF + (size_t)r * 16;
#pragma unroll
    for (int j = 0; j < 16; ++j) op[j] = (int)~(u32)a[j];
}

// ---------------- kernel D1: edge-conv1_5 (128->64, k=16) ----------------
__global__ __launch_bounds__(256) void edge5_kernel(const float* __restrict__ h1t,
        const int* __restrict__ idxF,
        const float* __restrict__ w15, const float* __restrict__ b15,
        const float* __restrict__ g15, const float* __restrict__ bb15,
        float* __restrict__ g64t) {
    __shared__ float wl[128 * 64];
    for (int i = threadIdx.x; i < 128 * 64; i += 256) wl[i] = w15[i];
    __syncthreads();
    int lane = threadIdx.x & 63;
    int pt = blockIdx.x * 4 + (threadIdx.x >> 6);
    int bt = pt >> 12;
    const float* hrow = h1t + ((size_t)pt << 6);
    float cl = hrow[lane];
    float base = b15[lane];
#pragma unroll
    for (int c = 0; c < 64; ++c) base = fmaf(wl[(64 + c) * 64 + lane], __shfl(cl, c), base);
    float sc = g15[lane] * INVBN, sh = bb15[lane];
    float a = -INFINITY;
    const int* nb = idxF + (size_t)pt * 16;
    const float* hb = h1t + ((size_t)bt << 18);   // bt*NP*64
    float nl = hb[((size_t)nb[0] << 6) + lane];   // prefetch first neighbor row
#pragma unroll 1
    for (int j = 0; j < 16; ++j) {
        float nl_cur = nl;
        if (j < 15) nl = hb[((size_t)nb[j + 1] << 6) + lane];  // prefetch next
        float dl = nl_cur - cl;
        float y = base;
#pragma unroll
        for (int c = 0; c < 64; ++c) y = fmaf(wl[c * 64 + lane], __shfl(dl, c), y);
        float z = fmaf(y, sc, sh);
        z = z >= 0.f ? z : 0.2f * z;
        a = fmaxf(a, z);
    }
    g64t[((size_t)pt << 6) + lane] = a;
}

// ---------------- kernel D2: conv1_4 + BN + lrelu + fc head + refine ----------------
__global__ __launch_bounds__(256) void head_kernel(const float* __restrict__ g64t,
        const float* __restrict__ point,
        const float* __restrict__ w14, const float* __restrict__ b14,
        const float* __restrict__ g14, const float* __restrict__ bb14,
        const float* __restrict__ wf1, const float* __restrict__ bf1,
        const float* __restrict__ wf2, const float* __restrict__ bf2,
        float* __restrict__ out) {
    __shared__ float w14l[64 * 128];
    __shared__ float wf1l[128 * 64];
    __shared__ float wf2l[64 * 3];
    for (int i = threadIdx.x; i < 8192; i += 256) { w14l[i] = w14[i]; wf1l[i] = wf1[i]; }
    for (int i = threadIdx.x; i < 192; i += 256) wf2l[i] = wf2[i];
    __syncthreads();
    int lane = threadIdx.x & 63;
    int pt = blockIdx.x * 4 + (threadIdx.x >> 6);
    int bt = pt >> 12, n = pt & (NP - 1);
    float gl = g64t[((size_t)pt << 6) + lane];
    float ylo = b14[lane], yhi = b14[64 + lane];
#pragma unroll
    for (int c = 0; c < 64; ++c) {
        float gc = __shfl(gl, c);
        ylo = fmaf(w14l[c * 128 + lane], gc, ylo);
        yhi = fmaf(w14l[c * 128 + 64 + lane], gc, yhi);
    }
    float flo = fmaf(ylo, g14[lane] * INVBN, bb14[lane]);
    flo = flo >= 0.f ? flo : 0.2f * flo;
    float fhi = fmaf(yhi, g14[64 + lane] * INVBN, bb14[64 + lane]);
    fhi = fhi >= 0.f ? fhi : 0.2f * fhi;
    out[((size_t)pt << 7) + lane] = flo;        // feat [B][N][128]
    out[((size_t)pt << 7) + 64 + lane] = fhi;
    float r = bf1[lane];
#pragma unroll
    for (int c = 0; c < 64; ++c) r = fmaf(wf1l[c * 64 + lane], __shfl(flo, c), r);
#pragma unroll
    for (int c = 0; c < 64; ++c) r = fmaf(wf1l[(64 + c) * 64 + lane], __shfl(fhi, c), r);
    r = fmaxf(r, 0.f);
    float h0 = 0.f, h1 = 0.f, h2 = 0.f;
#pragma unroll
    for (int c = 0; c < 64; ++c) {
        float rc = __shfl(r, c);
        h0 = fmaf(wf2l[c * 3 + 0], rc, h0);
        h1 = fmaf(wf2l[c * 3 + 1], rc, h1);
        h2 = fmaf(wf2l[c * 3 + 2], rc, h2);
    }
    if (lane < 3) {
        float hh = lane == 0 ? h0 : (lane == 1 ? h1 : h2);
        float p = point[((size_t)bt * 3 + lane) * NP + n];
        out[(size_t)FEAT_SZ + (size_t)pt * 3 + lane] = hh + bf2[lane] + p;
    }
}

extern "C" void kernel_launch(void* const* d_in, const int* in_sizes, int n_in,
                              void* d_out, int out_size, void* d_ws, size_t ws_size,
                              hipStream_t stream) {
    (void)in_sizes; (void)n_in; (void)out_size; (void)ws_size;
    const float* point = (const float*)d_in[0];
    const float* w11 = (const float*)d_in[1];
    const float* b11 = (const float*)d_in[2];
    const float* g11 = (const float*)d_in[3];
    const float* bb11 = (const float*)d_in[4];
    const float* w12 = (const float*)d_in[5];
    const float* b12 = (const float*)d_in[6];
    const float* g12 = (const float*)d_in[7];
    const float* bb12 = (const float*)d_in[8];
    const float* w13 = (const float*)d_in[9];
    const float* b13 = (const float*)d_in[10];
    const float* g13 = (const float*)d_in[11];
    const float* bb13 = (const float*)d_in[12];
    const float* w15 = (const float*)d_in[13];
    const float* b15 = (const float*)d_in[14];
    const float* g15 = (const float*)d_in[15];
    const float* bb15 = (const float*)d_in[16];
    const float* w14 = (const float*)d_in[17];
    const float* b14 = (const float*)d_in[18];
    const float* g14 = (const float*)d_in[19];
    const float* bb14 = (const float*)d_in[20];
    const float* wf1 = (const float*)d_in[21];
    const float* bf1 = (const float*)d_in[22];
    const float* wf2 = (const float*)d_in[23];
    const float* bf2 = (const float*)d_in[24];

    char* ws = (char*)d_ws;
    int*   idxP = (int*)ws;                         // 2 MiB
    int*   idxF = (int*)(ws + (2u << 20));          // 2 MiB
    float* h1t  = (float*)(ws + (4u << 20));        // 8 MiB  [B][N][64]
    float* g64t = (float*)(ws + (12u << 20));       // 8 MiB  [B][N][64]
    u64*   partF = (u64*)(ws + (12u << 20));        // 8 MiB  (aliases g64t; consumed by mergeF before edge5 writes)
    float* xxf  = (float*)(ws + (20u << 20));       // 128 KiB

    knn_point_kernel<<<dim3(NB * 128), dim3(256), 0, stream>>>(point, idxP);
    edge12_conv13_kernel<<<dim3(NB * NP / 4), dim3(256), 0, stream>>>(
        point, idxP, w11, b11, g11, bb11, w12, b12, g12, bb12,
        w13, b13, g13, bb13, h1t, xxf);
    knn_feat_kernel<<<dim3(NB * 64 * SPLIT), dim3(256), 0, stream>>>(h1t, xxf, partF);
    mergeF_kernel<<<dim3(NB * NP / 256), dim3(256), 0, stream>>>(partF, idxF);
    edge5_kernel<<<dim3(NB * NP / 4), dim3(256), 0, stream>>>(
        h1t, idxF, w15, b15, g15, bb15, g64t);
    head_kernel<<<dim3(NB * NP / 4), dim3(256), 0, stream>>>(
        g64t, point, w14, b14, g14, bb14, wf1, bf1, wf2, bf2, (float*)d_out);
}

// Round 6
// 1460.609 us; speedup vs baseline: 2.0821x; 2.0821x over previous
//
#include <hip/hip_runtime.h>
#include <math.h>

#define NB 8
#define NP 4096
#define FEAT_SZ (NB * NP * 128)
#define INVBN 0.9999950000374999f  // 1/sqrt(1+1e-5), f32-rounded
#define SPLIT 2
#define CHUNKS 32                  // 4096 cols / 64 / SPLIT

typedef unsigned long long u64;
typedef unsigned int u32;

// monotone map: float -> u32 preserving order (larger float -> larger u32)
__device__ __forceinline__ u32 fmap(float f) {
    u32 b = __float_as_uint(f);
    return b ^ ((u32)((int)b >> 31) | 0x80000000u);
}

__device__ __forceinline__ u64 umax64(u64 a, u64 b) { return a > b ? a : b; }

// insert key into descending-sorted v[16] if it beats the current 16th.
// key = (mapped_dist << 32) | ~m  -> tie-break: equal dist => smaller m wins.
__device__ __forceinline__ void kins(u64 (&v)[16], u64 key) {
    if (key <= v[15]) return;
    bool bb[16];
#pragma unroll
    for (int j = 0; j < 16; ++j) bb[j] = key > v[j];
#pragma unroll
    for (int j = 15; j >= 1; --j) v[j] = bb[j] ? (bb[j - 1] ? v[j - 1] : key) : v[j];
    if (bb[0]) v[0] = key;
}

// 4-deep register buffer append (static cndmask chain); overflow -> direct kins
__device__ __forceinline__ void bufpush(u64 (&v)[16], u64 &q0, u64 &q1, u64 &q2, u64 &q3,
                                        int &cnt, u64 key) {
    if (cnt < 4) {
        q0 = cnt == 0 ? key : q0;
        q1 = cnt == 1 ? key : q1;
        q2 = cnt == 2 ? key : q2;
        q3 = cnt == 3 ? key : q3;
        ++cnt;
    } else {
        kins(v, key);   // rare overflow fallback (exactness guarantee)
    }
}

__device__ __forceinline__ void bufflush(u64 (&v)[16], u64 &q0, u64 &q1, u64 &q2, u64 &q3,
                                         int &cnt) {
    kins(v, q0); kins(v, q1); kins(v, q2); kins(v, q3);
    q0 = 0; q1 = 0; q2 = 0; q3 = 0; cnt = 0;
}

// bitonic clean (desc) of a bitonic 16-sequence -> fully sorted desc
__device__ __forceinline__ void bclean(u64 (&v)[16]) {
#pragma unroll
    for (int d = 8; d; d >>= 1) {
#pragma unroll
        for (int i = 0; i < 16; ++i) {
            if ((i & d) == 0) {
                u64 a = v[i], b = v[i | d];
                bool s = a < b;
                v[i] = s ? b : a;
                v[i | d] = s ? a : b;
            }
        }
    }
}

// merge partner lane's sorted-16 (lane+off) into mine: pairwise-max + clean
__device__ __forceinline__ void merge_shfl(u64 (&v)[16], int off) {
    u64 o[16];
#pragma unroll
    for (int j = 0; j < 16; ++j) o[j] = __shfl_down(v[j], off);
#pragma unroll
    for (int j = 0; j < 16; ++j) {
        u64 b = o[15 - j];
        v[j] = v[j] > b ? v[j] : b;
    }
    bclean(v);
}

// max over the 8 consecutive lanes of a row
__device__ __forceinline__ u64 rowmax8(u64 x) {
    x = umax64(x, __shfl_xor(x, 1));
    x = umax64(x, __shfl_xor(x, 2));
    x = umax64(x, __shfl_xor(x, 4));
    return x;
}

// ---------------- kernel A: point-space kNN (k=16) ----------------
// grid 8*128, block 256. 32 rows/block, 8 threads/row (interleaved m-partition).
__global__ __launch_bounds__(256) void knn_point_kernel(const float* __restrict__ point,
                                                        int* __restrict__ idxP) {
    __shared__ float4 pts[NP];  // (x,y,z,xx)  64 KiB
    int bt = blockIdx.x >> 7;
    int n0 = (blockIdx.x & 127) << 5;
    const float* pb = point + (size_t)bt * 3 * NP;
    for (int m = threadIdx.x; m < NP; m += 256) {
        float x = pb[m], y = pb[NP + m], z = pb[2 * NP + m];
        pts[m] = make_float4(x, y, z, fmaf(z, z, fmaf(y, y, x * x)));
    }
    __syncthreads();
    int t = threadIdx.x;
    int q = t & 7;
    float4 c = pts[n0 + (t >> 3)];
    u64 v[16];
#pragma unroll
    for (int j = 0; j < 16; ++j) v[j] = 0;
    u64 b0 = 0, b1 = 0, b2 = 0, b3 = 0;
    int cnt = 0;
    u64 th = 0;
#pragma unroll 1
    for (int o = 0; o < 8; ++o) {
#pragma unroll 4
        for (int ii = 0; ii < 64; ++ii) {
            int m = (((o << 6) + ii) << 3) + q;
            float4 p = pts[m];
            float inner = fmaf(c.z, p.z, fmaf(c.y, p.y, c.x * p.x));
            float pd = fmaf(2.0f, inner, -c.w) - p.w;  // 2*inner - xx_n - xx_m
            u64 key = ((u64)fmap(pd) << 32) | (u64)(u32)~m;
            if (key > th) bufpush(v, b0, b1, b2, b3, cnt, key);
        }
        if (__any(cnt >= 3)) {
            bufflush(v, b0, b1, b2, b3, cnt);
            th = rowmax8(v[15]);
        }
    }
    bufflush(v, b0, b1, b2, b3, cnt);
    merge_shfl(v, 4);
    merge_shfl(v, 2);
    merge_shfl(v, 1);
    if (q == 0) {
        int* op = idxP + ((size_t)bt * NP + n0 + (t >> 3)) * 16;
#pragma unroll
        for (int j = 0; j < 16; ++j) op[j] = (int)~(u32)v[j];
    }
}

// ---------- kernel B: edge-conv1_1(k=8) + 1_2(k=16) + conv1_3, fused ----------
__global__ __launch_bounds__(256) void edge12_conv13_kernel(
    const float* __restrict__ point, const int* __restrict__ idxP,
    const float* __restrict__ w11, const float* __restrict__ b11,
    const float* __restrict__ g11, const float* __restrict__ bb11,
    const float* __restrict__ w12, const float* __restrict__ b12,
    const float* __restrict__ g12, const float* __restrict__ bb12,
    const float* __restrict__ w13, const float* __restrict__ b13,
    const float* __restrict__ g13, const float* __restrict__ bb13,
    float* __restrict__ h1t, float* __restrict__ xxf) {
    __shared__ float wl[128 * 64];
    for (int i = threadIdx.x; i < 128 * 64; i += 256) wl[i] = w13[i];
    __syncthreads();
    int lane = threadIdx.x & 63;
    int pt = blockIdx.x * 4 + (threadIdx.x >> 6);
    int bt = pt >> 12, n = pt & (NP - 1);
    const float* pb = point + (size_t)bt * 3 * NP;
    float wd1[3], wc1[3], wd2[3], wc2[3];
#pragma unroll
    for (int c = 0; c < 3; ++c) {
        wd1[c] = w11[c * 64 + lane]; wc1[c] = w11[(3 + c) * 64 + lane];
        wd2[c] = w12[c * 64 + lane]; wc2[c] = w12[(3 + c) * 64 + lane];
    }
    float s1 = g11[lane] * INVBN, sh1 = bb11[lane];
    float s2 = g12[lane] * INVBN, sh2 = bb12[lane];
    float cx = pb[n], cy = pb[NP + n], cz = pb[2 * NP + n];
    float base1 = fmaf(wc1[2], cz, fmaf(wc1[1], cy, fmaf(wc1[0], cx, b11[lane])));
    float base2 = fmaf(wc2[2], cz, fmaf(wc2[1], cy, fmaf(wc2[0], cx, b12[lane])));
    float a1 = -INFINITY, a2 = -INFINITY;
    const int* nb = idxP + (size_t)pt * 16;
#pragma unroll
    for (int j = 0; j < 16; ++j) {
        int m = nb[j];
        float ex = pb[m] - cx, ey = pb[NP + m] - cy, ez = pb[2 * NP + m] - cz;
        float y2 = fmaf(wd2[2], ez, fmaf(wd2[1], ey, fmaf(wd2[0], ex, base2)));
        float z2 = fmaf(y2, s2, sh2);
        z2 = z2 >= 0.f ? z2 : 0.2f * z2;
        a2 = fmaxf(a2, z2);
        if (j < 8) {  // top-8 is prefix of sorted top-16
            float y1 = fmaf(wd1[2], ez, fmaf(wd1[1], ey, fmaf(wd1[0], ex, base1)));
            float z1 = fmaf(y1, s1, sh1);
            z1 = z1 >= 0.f ? z1 : 0.2f * z1;
            a1 = fmaxf(a1, z1);
        }
    }
    float acc = b13[lane];
#pragma unroll
    for (int c = 0; c < 64; ++c) acc = fmaf(wl[c * 64 + lane], __shfl(a1, c), acc);
#pragma unroll
    for (int c = 0; c < 64; ++c) acc = fmaf(wl[(64 + c) * 64 + lane], __shfl(a2, c), acc);
    float h = fmaf(acc, g13[lane] * INVBN, bb13[lane]);
    h = h >= 0.f ? h : 0.2f * h;
    h1t[((size_t)pt << 6) + lane] = h;
    // xxf: ascending-FMA chain, bitwise-identical to the GEMM diagonal chain
    float s = 0.f;
#pragma unroll
    for (int c = 0; c < 64; ++c) { float hc = __shfl(h, c); s = fmaf(hc, hc, s); }
    if (lane == 0) xxf[pt] = s;
}

// ---------------- kernel C: feature-space kNN (C=64, k=16) ----------------
// Tile 128 rows x 64 cols/chunk. Thread GEMM-tile 8x4 (1.5 B/FMA from LDS).
// Compressed u32 keys round-trip through Sb; 2 collectors/row with gated
// buffered selection. LDS exactly 80KB -> 2 blocks/CU.
__global__ __launch_bounds__(256, 2) void knn_feat_kernel(const float* __restrict__ h1t,
                                                          const float* __restrict__ xxf,
                                                          u64* __restrict__ partF) {
    __shared__ __align__(16) char smem[81920];
    float* At = (float*)smem;                  // [64ch][128row swizzled] 32KB
    float* Bt = (float*)(smem + 32768);        // [64ch][64col swizzled]  16KB
    u32*   Sb = (u32*)(smem + 49152);          // [128row][64col swizzled] 32KB
    int seg = blockIdx.x & 1;
    int rg  = (blockIdx.x >> 1) & 31;
    int bt  = blockIdx.x >> 6;
    int n0  = rg << 7;
    int tid = threadIdx.x;
    int rp = tid >> 4;          // GEMM rows rp*8..+7
    int cg = tid & 15;          // GEMM cols cg*4..+3
    int cs = cg << 2;           // staging channel start (also uses rp as row idx)
    const float* hbase = h1t + ((size_t)bt * NP << 6);
    const float* hA = hbase + ((size_t)n0 << 6);
    // ---- prologue: stage A (128 rows x 64 ch, swizzled)
#pragma unroll
    for (int rep = 0; rep < 8; ++rep) {
        int row = rep * 16 + rp;
        float4 va = *(const float4*)(hA + (row << 6) + cs);
        float fv[4] = {va.x, va.y, va.z, va.w};
#pragma unroll
        for (int i = 0; i < 4; ++i) {
            int ch = cs + i;
            int rw = row ^ ((row & 32) >> 3) ^ (((ch >> 2) & 7) << 2);
            At[ch * 128 + rw] = fv[i];
        }
    }
    int m00 = seg * (CHUNKS * 64);
    // stage B chunk 0
#pragma unroll
    for (int rep = 0; rep < 4; ++rep) {
        int col = rep * 16 + rp;
        float4 vb = *(const float4*)(hbase + ((size_t)(m00 + col) << 6) + cs);
        float fv[4] = {vb.x, vb.y, vb.z, vb.w};
#pragma unroll
        for (int i = 0; i < 4; ++i) {
            int ch = cs + i;
            int cl = col ^ ((col & 32) >> 3) ^ (((ch >> 2) & 7) << 2);
            Bt[ch * 64 + cl] = fv[i];
        }
    }
    // xa for my 8 GEMM rows
    float xa[8];
    {
        const float* xap = xxf + bt * NP + n0 + rp * 8;
        float4 t0 = *(const float4*)xap;
        float4 t1 = *(const float4*)(xap + 4);
        xa[0]=t0.x; xa[1]=t0.y; xa[2]=t0.z; xa[3]=t0.w;
        xa[4]=t1.x; xa[5]=t1.y; xa[6]=t1.z; xa[7]=t1.w;
    }
    // collector identity: row r (two owners), col-half h
    int r = tid >> 1, h = tid & 1;
    u64 v[16];
#pragma unroll
    for (int j = 0; j < 16; ++j) v[j] = 0;
    u64 q0 = 0, q1 = 0, q2 = 0, q3 = 0;
    int cnt = 0;
    u32 th32 = 0;
    int ab0 = (rp * 8) ^ (rp & 4);          // swizzled base, rows rp*8..+3
    int ab1 = (rp * 8 + 4) ^ (rp & 4);      // rows rp*8+4..+7
    int cb0 = (cg * 4) ^ ((cg & 8) >> 1);   // swizzled base, cols cg*4..+3
    int swQ = ((r ^ (r >> 3)) & 7) << 2;    // Sb collector swizzle
    __syncthreads();
#pragma unroll 1
    for (int mcl = 0; mcl < CHUNKS; ++mcl) {
        int m0c = m00 + (mcl << 6);
        bool more = (mcl + 1) < CHUNKS;
        float4 nv0, nv1, nv2, nv3;          // next-B, issued early (hidden by GEMM)
        if (more) {
            const float* hn = hbase + ((size_t)(m0c + 64) << 6);
            nv0 = *(const float4*)(hn + ((0 * 16 + rp) << 6) + cs);
            nv1 = *(const float4*)(hn + ((1 * 16 + rp) << 6) + cs);
            nv2 = *(const float4*)(hn + ((2 * 16 + rp) << 6) + cs);
            nv3 = *(const float4*)(hn + ((3 * 16 + rp) << 6) + cs);
        }
        float4 xbv = *(const float4*)(xxf + bt * NP + m0c + (cg << 2));
        float acc[8][4];
#pragma unroll
        for (int i = 0; i < 8; ++i)
#pragma unroll
            for (int j = 0; j < 4; ++j) acc[i][j] = 0.f;
#pragma unroll 4
        for (int kk = 0; kk < 64; ++kk) {
            int sw = ((kk >> 2) & 7) << 2;
            const float* Ak = At + (kk << 7);
            float4 a0 = *(const float4*)(Ak + (ab0 ^ sw));
            float4 a1 = *(const float4*)(Ak + (ab1 ^ sw));
            float4 b  = *(const float4*)(Bt + (kk << 6) + (cb0 ^ sw));
            float av[8] = {a0.x, a0.y, a0.z, a0.w, a1.x, a1.y, a1.z, a1.w};
            float bv[4] = {b.x, b.y, b.z, b.w};
#pragma unroll
            for (int i = 0; i < 8; ++i)
#pragma unroll
                for (int j = 0; j < 4; ++j)
                    acc[i][j] = fmaf(av[i], bv[j], acc[i][j]);   // ascending-kk chain
        }
        // keys -> Sb (compressed u32)
        float xbs[4] = {xbv.x, xbv.y, xbv.z, xbv.w};
#pragma unroll
        for (int i = 0; i < 8; ++i) {
            int row = rp * 8 + i;
            u32 k0, k1, k2, k3;
            {
                float pd;
                pd = fmaf(2.0f, acc[i][0], -xa[i]) - xbs[0]; k0 = fmap(pd);
                pd = fmaf(2.0f, acc[i][1], -xa[i]) - xbs[1]; k1 = fmap(pd);
                pd = fmaf(2.0f, acc[i][2], -xa[i]) - xbs[2]; k2 = fmap(pd);
                pd = fmaf(2.0f, acc[i][3], -xa[i]) - xbs[3]; k3 = fmap(pd);
            }
            int sq = ((row ^ (row >> 3)) & 7) << 2;
            *(uint4*)(Sb + row * 64 + ((cg << 2) ^ sq)) = make_uint4(k0, k1, k2, k3);
        }
        __syncthreads();   // Sb complete; Bt reads done
        // collect my row-half (gate vs shared u32 threshold; exact)
#pragma unroll
        for (int s = 0; s < 8; ++s) {
            int c0 = h * 32 + (s << 2);
            uint4 kq = *(const uint4*)(Sb + r * 64 + (c0 ^ swQ));
            u32 ks[4] = {kq.x, kq.y, kq.z, kq.w};
#pragma unroll
            for (int j = 0; j < 4; ++j) {
                if (ks[j] >= th32) {
                    u64 key = ((u64)ks[j] << 32) | (u64)(u32)~(m0c + c0 + j);
                    bufpush(v, q0, q1, q2, q3, cnt, key);
                }
            }
        }
        // write next B tile (regions disjoint from Sb reads)
        if (more) {
            float fva[4][4] = {{nv0.x, nv0.y, nv0.z, nv0.w}, {nv1.x, nv1.y, nv1.z, nv1.w},
                               {nv2.x, nv2.y, nv2.z, nv2.w}, {nv3.x, nv3.y, nv3.z, nv3.w}};
#pragma unroll
            for (int rep = 0; rep < 4; ++rep) {
                int col = rep * 16 + rp;
#pragma unroll
                for (int i = 0; i < 4; ++i) {
                    int ch = cs + i;
                    int cl = col ^ ((col & 32) >> 3) ^ (((ch >> 2) & 7) << 2);
                    Bt[ch * 64 + cl] = fva[rep][i];
                }
            }
        }
        if (__any(cnt >= 3)) {
            bufflush(v, q0, q1, q2, q3, cnt);
            u64 m = umax64(v[15], __shfl_xor(v[15], 1));  // shared across halves: exact
            th32 = (u32)(m >> 32);
        }
        __syncthreads();
    }
    bufflush(v, q0, q1, q2, q3, cnt);
    merge_shfl(v, 1);   // merge the two col-halves of row r
    if (h == 0) {
        u64* op = partF + (((size_t)bt * NP + n0 + r) * SPLIT + seg) * 16;
#pragma unroll
        for (int j = 0; j < 16; ++j) op[j] = v[j];
    }
}

// ---------------- kernel C2: merge the SPLIT partial lists per row ----------------
__global__ __launch_bounds__(256) void mergeF_kernel(const u64* __restrict__ partF,
                                                     int* __restrict__ idxF) {
    int r = blockIdx.x * 256 + threadIdx.x;   // 0..NB*NP-1
    const u64* base = partF + (size_t)r * (SPLIT * 16);
    u64 a[16];
#pragma unroll
    for (int j = 0; j < 16; ++j) a[j] = base[j];
    u64 b[16];
#pragma unroll
    for (int j = 0; j < 16; ++j) b[j] = base[16 + j];
#pragma unroll
    for (int j = 0; j < 16; ++j) {
        u64 x = b[15 - j];
        a[j] = a[j] > x ? a[j] : x;
    }
    bclean(a);
    int* op = idxF + (size_t)r * 16;
#pragma unroll
    for (int j = 0; j < 16; ++j) op[j] = (int)~(u32)a[j];
}

// ---------------- kernel D1: edge-conv1_5 (128->64, k=16) ----------------
__global__ __launch_bounds__(256) void edge5_kernel(const float* __restrict__ h1t,
        const int* __restrict__ idxF,
        const float* __restrict__ w15, const float* __restrict__ b15,
        const float* __restrict__ g15, const float* __restrict__ bb15,
        float* __restrict__ g64t) {
    __shared__ float wl[128 * 64];
    for (int i = threadIdx.x; i < 128 * 64; i += 256) wl[i] = w15[i];
    __syncthreads();
    int lane = threadIdx.x & 63;
    int pt = blockIdx.x * 4 + (threadIdx.x >> 6);
    int bt = pt >> 12;
    const float* hrow = h1t + ((size_t)pt << 6);
    float cl = hrow[lane];
    float base = b15[lane];
#pragma unroll
    for (int c = 0; c < 64; ++c) base = fmaf(wl[(64 + c) * 64 + lane], __shfl(cl, c), base);
    float sc = g15[lane] * INVBN, sh = bb15[lane];
    float a = -INFINITY;
    const int* nb = idxF + (size_t)pt * 16;
    const float* hb = h1t + ((size_t)bt << 18);   // bt*NP*64
    float nl = hb[((size_t)nb[0] << 6) + lane];   // prefetch first neighbor row
#pragma unroll 1
    for (int j = 0; j < 16; ++j) {
        float nl_cur = nl;
        if (j < 15) nl = hb[((size_t)nb[j + 1] << 6) + lane];  // prefetch next
        float dl = nl_cur - cl;
        float y = base;
#pragma unroll
        for (int c = 0; c < 64; ++c) y = fmaf(wl[c * 64 + lane], __shfl(dl, c), y);
        float z = fmaf(y, sc, sh);
        z = z >= 0.f ? z : 0.2f * z;
        a = fmaxf(a, z);
    }
    g64t[((size_t)pt << 6) + lane] = a;
}

// ---------------- kernel D2: conv1_4 + BN + lrelu + fc head + refine ----------------
__global__ __launch_bounds__(256) void head_kernel(const float* __restrict__ g64t,
        const float* __restrict__ point,
        const float* __restrict__ w14, const float* __restrict__ b14,
        const float* __restrict__ g14, const float* __restrict__ bb14,
        const float* __restrict__ wf1, const float* __restrict__ bf1,
        const float* __restrict__ wf2, const float* __restrict__ bf2,
        float* __restrict__ out) {
    __shared__ float w14l[64 * 128];
    __shared__ float wf1l[128 * 64];
    __shared__ float wf2l[64 * 3];
    for (int i = threadIdx.x; i < 8192; i += 256) { w14l[i] = w14[i]; wf1l[i] = wf1[i]; }
    for (int i = threadIdx.x; i < 192; i += 256) wf2l[i] = wf2[i];
    __syncthreads();
    int lane = threadIdx.x & 63;
    int pt = blockIdx.x * 4 + (threadIdx.x >> 6);
    int bt = pt >> 12, n = pt & (NP - 1);
    float gl = g64t[((size_t)pt << 6) + lane];
    float ylo = b14[lane], yhi = b14[64 + lane];
#pragma unroll
    for (int c = 0; c < 64; ++c) {
        float gc = __shfl(gl, c);
        ylo = fmaf(w14l[c * 128 + lane], gc, ylo);
        yhi = fmaf(w14l[c * 128 + 64 + lane], gc, yhi);
    }
    float flo = fmaf(ylo, g14[lane] * INVBN, bb14[lane]);
    flo = flo >= 0.f ? flo : 0.2f * flo;
    float fhi = fmaf(yhi, g14[64 + lane] * INVBN, bb14[64 + lane]);
    fhi = fhi >= 0.f ? fhi : 0.2f * fhi;
    out[((size_t)pt << 7) + lane] = flo;        // feat [B][N][128]
    out[((size_t)pt << 7) + 64 + lane] = fhi;
    float r = bf1[lane];
#pragma unroll
    for (int c = 0; c < 64; ++c) r = fmaf(wf1l[c * 64 + lane], __shfl(flo, c), r);
#pragma unroll
    for (int c = 0; c < 64; ++c) r = fmaf(wf1l[(64 + c) * 64 + lane], __shfl(fhi, c), r);
    r = fmaxf(r, 0.f);
    float h0 = 0.f, h1 = 0.f, h2 = 0.f;
#pragma unroll
    for (int c = 0; c < 64; ++c) {
        float rc = __shfl(r, c);
        h0 = fmaf(wf2l[c * 3 + 0], rc, h0);
        h1 = fmaf(wf2l[c * 3 + 1], rc, h1);
        h2 = fmaf(wf2l[c * 3 + 2], rc, h2);
    }
    if (lane < 3) {
        float hh = lane == 0 ? h0 : (lane == 1 ? h1 : h2);
        float p = point[((size_t)bt * 3 + lane) * NP + n];
        out[(size_t)FEAT_SZ + (size_t)pt * 3 + lane] = hh + bf2[lane] + p;
    }
}

extern "C" void kernel_launch(void* const* d_in, const int* in_sizes, int n_in,
                              void* d_out, int out_size, void* d_ws, size_t ws_size,
                              hipStream_t stream) {
    (void)in_sizes; (void)n_in; (void)out_size; (void)ws_size;
    const float* point = (const float*)d_in[0];
    const float* w11 = (const float*)d_in[1];
    const float* b11 = (const float*)d_in[2];
    const float* g11 = (const float*)d_in[3];
    const float* bb11 = (const float*)d_in[4];
    const float* w12 = (const float*)d_in[5];
    const float* b12 = (const float*)d_in[6];
    const float* g12 = (const float*)d_in[7];
    const float* bb12 = (const float*)d_in[8];
    const float* w13 = (const float*)d_in[9];
    const float* b13 = (const float*)d_in[10];
    const float* g13 = (const float*)d_in[11];
    const float* bb13 = (const float*)d_in[12];
    const float* w15 = (const float*)d_in[13];
    const float* b15 = (const float*)d_in[14];
    const float* g15 = (const float*)d_in[15];
    const float* bb15 = (const float*)d_in[16];
    const float* w14 = (const float*)d_in[17];
    const float* b14 = (const float*)d_in[18];
    const float* g14 = (const float*)d_in[19];
    const float* bb14 = (const float*)d_in[20];
    const float* wf1 = (const float*)d_in[21];
    const float* bf1 = (const float*)d_in[22];
    const float* wf2 = (const float*)d_in[23];
    const float* bf2 = (const float*)d_in[24];

    char* ws = (char*)d_ws;
    int*   idxP = (int*)ws;                         // 2 MiB
    int*   idxF = (int*)(ws + (2u << 20));          // 2 MiB
    float* h1t  = (float*)(ws + (4u << 20));        // 8 MiB  [B][N][64]
    float* g64t = (float*)(ws + (12u << 20));       // 8 MiB  [B][N][64]
    u64*   partF = (u64*)(ws + (12u << 20));        // 8 MiB  (aliases g64t; consumed by mergeF before edge5 writes)
    float* xxf  = (float*)(ws + (20u << 20));       // 128 KiB

    knn_point_kernel<<<dim3(NB * 128), dim3(256), 0, stream>>>(point, idxP);
    edge12_conv13_kernel<<<dim3(NB * NP / 4), dim3(256), 0, stream>>>(
        point, idxP, w11, b11, g11, bb11, w12, b12, g12, bb12,
        w13, b13, g13, bb13, h1t, xxf);
    knn_feat_kernel<<<dim3(NB * 32 * SPLIT), dim3(256), 0, stream>>>(h1t, xxf, partF);
    mergeF_kernel<<<dim3(NB * NP / 256), dim3(256), 0, stream>>>(partF, idxF);
    edge5_kernel<<<dim3(NB * NP / 4), dim3(256), 0, stream>>>(
        h1t, idxF, w15, b15, g15, bb15, g64t);
    head_kernel<<<dim3(NB * NP / 4), dim3(256), 0, stream>>>(
        g64t, point, w14, b14, g14, bb14, wf1, bf1, wf2, bf2, (float*)d_out);
}